// Round 12
// baseline (14.664 us; speedup 1.0000x reference)
//
#include <hip/hip_runtime.h>

#define NJ 32
#define BLK 256

// ---- Minimal-form segmented (32-lane) inclusive prefix scans ----
// 5 x v_add_f32_dpp per scan; 4-12 independent chains interleaved per asm
// block so dependent DPP ops are >=3 issue slots apart (covers the
// gfx9-lineage VALU->DPP hazard without nops). bound_ctrl:0 zeroes
// out-of-range reads (scan identity); row_bcast:15 row_mask:0xa stitches
// the two 16-lane halves of each 32-lane segment.

#define MODS1 "row_shr:1 row_mask:0xf bank_mask:0xf bound_ctrl:0"
#define MODS2 "row_shr:2 row_mask:0xf bank_mask:0xf bound_ctrl:0"
#define MODS4 "row_shr:4 row_mask:0xf bank_mask:0xf bound_ctrl:0"
#define MODS8 "row_shr:8 row_mask:0xf bank_mask:0xf bound_ctrl:0"
#define MODSB "row_bcast:15 row_mask:0xa bank_mask:0xf"

#define D(n,m) "v_add_f32_dpp %" #n ", %" #n ", %" #n " " m "\n\t"

#define STEP12(m) D(0,m) D(1,m) D(2,m) D(3,m) D(4,m) D(5,m) D(6,m) D(7,m) \
                  D(8,m) D(9,m) D(10,m) D(11,m)
#define STEP8(m)  D(0,m) D(1,m) D(2,m) D(3,m) D(4,m) D(5,m) D(6,m) D(7,m)
#define STEP4(m)  D(0,m) D(1,m) D(2,m) D(3,m)

__device__ __forceinline__ void scan12(float& a, float& b, float& c, float& d,
                                       float& e, float& f, float& g, float& h,
                                       float& i, float& j, float& k, float& l) {
    asm("s_nop 1\n\t"
        STEP12(MODS1) STEP12(MODS2) STEP12(MODS4) STEP12(MODS8) STEP12(MODSB)
        : "+v"(a), "+v"(b), "+v"(c), "+v"(d), "+v"(e), "+v"(f),
          "+v"(g), "+v"(h), "+v"(i), "+v"(j), "+v"(k), "+v"(l));
}

__device__ __forceinline__ void scan8(float& a, float& b, float& c, float& d,
                                      float& e, float& f, float& g, float& h) {
    asm("s_nop 1\n\t"
        STEP8(MODS1) STEP8(MODS2) STEP8(MODS4) STEP8(MODS8) STEP8(MODSB)
        : "+v"(a), "+v"(b), "+v"(c), "+v"(d),
          "+v"(e), "+v"(f), "+v"(g), "+v"(h));
}

__device__ __forceinline__ void scan4(float& a, float& b, float& c, float& d) {
    asm("s_nop 1\n\t"
        STEP4(MODS1) STEP4(MODS2) STEP4(MODS4) STEP4(MODS8) STEP4(MODSB)
        : "+v"(a), "+v"(b), "+v"(c), "+v"(d));
}

// Segment totals after an inclusive scan live in lanes 31 / 63 (VALU-only).
__device__ __forceinline__ float seg_total(float x, int hiHalf) {
    int lo, hi;
    asm("s_nop 1\n\t"
        "v_readlane_b32 %0, %2, 31\n\t"
        "v_readlane_b32 %1, %2, 63"
        : "=s"(lo), "=s"(hi) : "v"(x));
    return __int_as_float(hiHalf ? hi : lo);
}

// Shift whole wave down one lane (lane i <- lane i-1); wave lane 0 gets 0.
__device__ __forceinline__ float wave_shr1(float x) {
    return __int_as_float(
        __builtin_amdgcn_update_dpp(0, __float_as_int(x), 0x138, 0xf, 0xf, false));
}

// Native HW sincos (revolutions + fract reduction).
__device__ __forceinline__ void fast_sincos(float x, float& s, float& c) {
    float r = __builtin_amdgcn_fractf(x * 0.15915494309189535f);
    s = __builtin_amdgcn_sinf(r);
    c = __builtin_amdgcn_cosf(r);
}

__global__ __launch_bounds__(BLK) void rnea_kernel(
    const float* __restrict__ q,
    const float* __restrict__ qd,
    const float* __restrict__ qdd,
    const float* __restrict__ trans,
    const float* __restrict__ mass,
    const float* __restrict__ com,
    const float* __restrict__ inertia,
    const float* __restrict__ damping,
    float* __restrict__ out,
    int Bn)
{
    const int t    = blockIdx.x * BLK + threadIdx.x;
    const int lane = threadIdx.x & 31;          // joint index
    const int hiH  = (threadIdx.x >> 5) & 1;    // which 32-lane segment
    const int qtr  = Bn >> 2;
    const int r0   = t >> 5;
    if (r0 >= qtr) return;
    const size_t stride = (size_t)qtr * NJ;
    const size_t i0 = (size_t)r0 * NJ + lane;   // all four coalesced
    const size_t i1 = i0 + stride;
    const size_t i2 = i1 + stride;
    const size_t i3 = i2 + stride;

    // Issue all global loads up front (12 independent row loads).
    float q0 = q[i0], q1 = q[i1], q2 = q[i2], q3 = q[i3];
    float qd0 = qd[i0], qd1 = qd[i1], qd2 = qd[i2], qd3 = qd[i3];
    float qdd0 = qdd[i0], qdd1 = qdd[i1], qdd2 = qdd[i2], qdd3 = qdd[i3];

    // Per-joint constants, gathered once, shared by all four rows.
    float m    = mass[lane];
    float cx   = com[3*lane+0], cy = com[3*lane+1];
    float mcx  = m*cx, mcy = m*cy;
    float i2zz = fmaf(m, cx*cx + cy*cy, inertia[9*lane+8]);   // Ibar_zz
    float px   = trans[3*lane+0], py = trans[3*lane+1];
    float damp = damping[lane];
    const bool seg0 = (lane == 0);

    // ---- Stage A: 12 independent prefix scans (phi, w, alpha x 4 rows).
    float phi0 = q0, phi1 = q1, phi2 = q2, phi3 = q3;
    float wI0 = qd0, wI1 = qd1, wI2 = qd2, wI3 = qd3;
    float aI0 = qdd0, aI1 = qdd1, aI2 = qdd2, aI3 = qdd3;
    scan12(phi0, phi1, phi2, phi3, wI0, wI1, wI2, wI3, aI0, aI1, aI2, aI3);
    float wP0 = wI0 - qd0, wP1 = wI1 - qd1, wP2 = wI2 - qd2, wP3 = wI3 - qd3;
    float aP0 = aI0 - qdd0, aP1 = aI1 - qdd1, aP2 = aI2 - qdd2, aP3 = aI3 - qdd3;

    float c0,s0,c1,s1,c2,s2,c3,s3;
    fast_sincos(phi0, s0, c0);
    fast_sincos(phi1, s1, c1);
    fast_sincos(phi2, s2, c2);
    fast_sincos(phi3, s3, c3);
    float cp0 = wave_shr1(c0), sp0 = wave_shr1(s0);
    float cp1 = wave_shr1(c1), sp1 = wave_shr1(s1);
    float cp2 = wave_shr1(c2), sp2 = wave_shr1(s2);
    float cp3 = wave_shr1(c3), sp3 = wave_shr1(s3);
    cp0 = seg0 ? 1.f : cp0;  sp0 = seg0 ? 0.f : sp0;
    cp1 = seg0 ? 1.f : cp1;  sp1 = seg0 ? 0.f : sp1;
    cp2 = seg0 ? 1.f : cp2;  sp2 = seg0 ? 0.f : sp2;
    cp3 = seg0 ? 1.f : cp3;  sp3 = seg0 ? 0.f : sp3;

    // d_j = Rz(phi_{j-1}) * p_j
    float dx0 = cp0*px - sp0*py, dy0 = sp0*px + cp0*py;
    float dx1 = cp1*px - sp1*py, dy1 = sp1*px + cp1*py;
    float dx2 = cp2*px - sp2*py, dy2 = sp2*px + cp2*py;
    float dx3 = cp3*px - sp3*py, dy3 = sp3*px + cp3*py;

    // ---- Stage B: VL scans (8 chains).
    float VLx0 = -wP0*dy0, VLy0 = wP0*dx0;
    float VLx1 = -wP1*dy1, VLy1 = wP1*dx1;
    float VLx2 = -wP2*dy2, VLy2 = wP2*dx2;
    float VLx3 = -wP3*dy3, VLy3 = wP3*dx3;
    scan8(VLx0, VLy0, VLx1, VLy1, VLx2, VLy2, VLx3, VLy3);

    // ---- Stage C: AL scans (8 chains).
    float ALx0 = fmaf(-aP0, dy0,  qd0*VLy0);
    float ALy0 = fmaf( aP0, dx0, -qd0*VLx0);
    float ALx1 = fmaf(-aP1, dy1,  qd1*VLy1);
    float ALy1 = fmaf( aP1, dx1, -qd1*VLx1);
    float ALx2 = fmaf(-aP2, dy2,  qd2*VLy2);
    float ALy2 = fmaf( aP2, dx2, -qd2*VLx2);
    float ALx3 = fmaf(-aP3, dy3,  qd3*VLy3);
    float ALy3 = fmaf( aP3, dx3, -qd3*VLx3);
    scan8(ALx0, ALy0, ALx1, ALy1, ALx2, ALy2, ALx3, ALy3);

    // ---- Backward (world frame, z-chain only).
    float mcwx0 = c0*mcx - s0*mcy, mcwy0 = s0*mcx + c0*mcy;
    float mcwx1 = c1*mcx - s1*mcy, mcwy1 = s1*mcx + c1*mcy;
    float mcwx2 = c2*mcx - s2*mcy, mcwy2 = s2*mcx + c2*mcy;
    float mcwx3 = c3*mcx - s3*mcy, mcwy3 = s3*mcx + c3*mcy;

    float fv_lx0 = fmaf(m, VLx0,  wI0*mcwy0), fv_ly0 = fmaf(m, VLy0, -wI0*mcwx0);
    float fv_lx1 = fmaf(m, VLx1,  wI1*mcwy1), fv_ly1 = fmaf(m, VLy1, -wI1*mcwx1);
    float fv_lx2 = fmaf(m, VLx2,  wI2*mcwy2), fv_ly2 = fmaf(m, VLy2, -wI2*mcwx2);
    float fv_lx3 = fmaf(m, VLx3,  wI3*mcwy3), fv_ly3 = fmaf(m, VLy3, -wI3*mcwx3);

    float llx0 = fmaf(m, ALx0, fmaf( aI0, mcwy0, -wI0*fv_ly0));
    float lly0 = fmaf(m, ALy0, fmaf(-aI0, mcwx0,  wI0*fv_lx0));
    float llx1 = fmaf(m, ALx1, fmaf( aI1, mcwy1, -wI1*fv_ly1));
    float lly1 = fmaf(m, ALy1, fmaf(-aI1, mcwx1,  wI1*fv_lx1));
    float llx2 = fmaf(m, ALx2, fmaf( aI2, mcwy2, -wI2*fv_ly2));
    float lly2 = fmaf(m, ALy2, fmaf(-aI2, mcwx2,  wI2*fv_lx2));
    float llx3 = fmaf(m, ALx3, fmaf( aI3, mcwy3, -wI3*fv_ly3));
    float lly3 = fmaf(m, ALy3, fmaf(-aI3, mcwx3,  wI3*fv_lx3));

    // ---- Stage D: force prefix scans (8 chains); suffix via totals.
    float Px0 = llx0, Py0 = lly0, Px1 = llx1, Py1 = lly1;
    float Px2 = llx2, Py2 = lly2, Px3 = llx3, Py3 = lly3;
    scan8(Px0, Py0, Px1, Py1, Px2, Py2, Px3, Py3);
    float Fx0 = seg_total(Px0, hiH) - Px0 + llx0;
    float Fy0 = seg_total(Py0, hiH) - Py0 + lly0;
    float Fx1 = seg_total(Px1, hiH) - Px1 + llx1;
    float Fy1 = seg_total(Py1, hiH) - Py1 + lly1;
    float Fx2 = seg_total(Px2, hiH) - Px2 + llx2;
    float Fy2 = seg_total(Py2, hiH) - Py2 + lly2;
    float Fx3 = seg_total(Px3, hiH) - Px3 + llx3;
    float Fy3 = seg_total(Py3, hiH) - Py3 + lly3;

    // ---- Stage E: z-moment chains (4 chains).
    float a0 = fmaf(aI0, i2zz, mcwx0*ALy0 - mcwy0*ALx0 + VLx0*fv_ly0 - VLy0*fv_lx0);
    float a1 = fmaf(aI1, i2zz, mcwx1*ALy1 - mcwy1*ALx1 + VLx1*fv_ly1 - VLy1*fv_lx1);
    float a2 = fmaf(aI2, i2zz, mcwx2*ALy2 - mcwy2*ALx2 + VLx2*fv_ly2 - VLy2*fv_lx2);
    float a3 = fmaf(aI3, i2zz, mcwx3*ALy3 - mcwy3*ALx3 + VLx3*fv_ly3 - VLy3*fv_lx3);
    float b0 = dx0*Fy0 - dy0*Fx0;
    float b1 = dx1*Fy1 - dy1*Fx1;
    float b2 = dx2*Fy2 - dy2*Fx2;
    float b3 = dx3*Fy3 - dy3*Fx3;
    float Pr0 = a0 + b0, Pr1 = a1 + b1, Pr2 = a2 + b2, Pr3 = a3 + b3;
    scan4(Pr0, Pr1, Pr2, Pr3);
    // Nz = suffix(a+b) - b = T - Pr + (a+b) - b = T - Pr + a
    float Nz0 = seg_total(Pr0, hiH) - Pr0 + a0;
    float Nz1 = seg_total(Pr1, hiH) - Pr1 + a1;
    float Nz2 = seg_total(Pr2, hiH) - Pr2 + a2;
    float Nz3 = seg_total(Pr3, hiH) - Pr3 + a3;

    out[i0] = fmaf(damp, qd0, Nz0);
    out[i1] = fmaf(damp, qd1, Nz1);
    out[i2] = fmaf(damp, qd2, Nz2);
    out[i3] = fmaf(damp, qd3, Nz3);
}

extern "C" void kernel_launch(void* const* d_in, const int* in_sizes, int n_in,
                              void* d_out, int out_size, void* d_ws, size_t ws_size,
                              hipStream_t stream) {
    const float* q       = (const float*)d_in[0];
    const float* qd      = (const float*)d_in[1];
    const float* qdd     = (const float*)d_in[2];
    const float* trans   = (const float*)d_in[3];
    const float* mass    = (const float*)d_in[4];
    const float* com     = (const float*)d_in[5];
    const float* inertia = (const float*)d_in[6];
    const float* damping = (const float*)d_in[7];
    float* out = (float*)d_out;

    int Bn = in_sizes[0] / NJ;
    long long threads = (long long)(Bn/4) * 32;
    int grid = (int)((threads + BLK - 1) / BLK);
    hipLaunchKernelGGL(rnea_kernel, dim3(grid), dim3(BLK), 0, stream,
                       q, qd, qdd, trans, mass, com, inertia, damping, out, Bn);
}

// Round 13
// 13.539 us; speedup vs baseline: 1.0831x; 1.0831x over previous
//
#include <hip/hip_runtime.h>

#define NJ 32
#define BLK 256

typedef float f2 __attribute__((ext_vector_type(2)));
__device__ __forceinline__ f2 mk2(float x, float y){ f2 r; r.x=x; r.y=y; return r; }

// ---- Minimal-form segmented (32-lane) inclusive prefix scans ----
// 5 x v_add_f32_dpp per scan; 2-6 independent chains interleaved per asm
// block so dependent DPP ops are >=2 issue slots apart (gfx9-lineage
// VALU->DPP hazard). bound_ctrl:0 zeroes out-of-range reads (scan identity);
// row_bcast:15 row_mask:0xa stitches the two 16-lane halves of each segment.

#define MODS1 "row_shr:1 row_mask:0xf bank_mask:0xf bound_ctrl:0"
#define MODS2 "row_shr:2 row_mask:0xf bank_mask:0xf bound_ctrl:0"
#define MODS4 "row_shr:4 row_mask:0xf bank_mask:0xf bound_ctrl:0"
#define MODS8 "row_shr:8 row_mask:0xf bank_mask:0xf bound_ctrl:0"
#define MODSB "row_bcast:15 row_mask:0xa bank_mask:0xf"

#define STEP6(m) \
  "v_add_f32_dpp %0, %0, %0 " m "\n\t" \
  "v_add_f32_dpp %1, %1, %1 " m "\n\t" \
  "v_add_f32_dpp %2, %2, %2 " m "\n\t" \
  "v_add_f32_dpp %3, %3, %3 " m "\n\t" \
  "v_add_f32_dpp %4, %4, %4 " m "\n\t" \
  "v_add_f32_dpp %5, %5, %5 " m "\n\t"

#define STEP4(m) \
  "v_add_f32_dpp %0, %0, %0 " m "\n\t" \
  "v_add_f32_dpp %1, %1, %1 " m "\n\t" \
  "v_add_f32_dpp %2, %2, %2 " m "\n\t" \
  "v_add_f32_dpp %3, %3, %3 " m "\n\t"

#define STEP2(m) \
  "v_add_f32_dpp %0, %0, %0 " m "\n\t" \
  "v_add_f32_dpp %1, %1, %1 " m "\n\t" \
  "s_nop 0\n\t"

__device__ __forceinline__ void scan6(float& a, float& b, float& c,
                                      float& d, float& e, float& f) {
    asm("s_nop 1\n\t"
        STEP6(MODS1) STEP6(MODS2) STEP6(MODS4) STEP6(MODS8) STEP6(MODSB)
        : "+v"(a), "+v"(b), "+v"(c), "+v"(d), "+v"(e), "+v"(f));
}

__device__ __forceinline__ void scan4(float& a, float& b, float& c, float& d) {
    asm("s_nop 1\n\t"
        STEP4(MODS1) STEP4(MODS2) STEP4(MODS4) STEP4(MODS8) STEP4(MODSB)
        : "+v"(a), "+v"(b), "+v"(c), "+v"(d));
}

__device__ __forceinline__ void scan2(float& a, float& b) {
    asm("s_nop 1\n\t"
        STEP2(MODS1) STEP2(MODS2) STEP2(MODS4) STEP2(MODS8) STEP2(MODSB)
        : "+v"(a), "+v"(b));
}

// Segment totals after an inclusive scan live in lanes 31 / 63 (VALU-only).
__device__ __forceinline__ float seg_total(float x, int hiHalf) {
    int lo, hi;
    asm("s_nop 1\n\t"
        "v_readlane_b32 %0, %2, 31\n\t"
        "v_readlane_b32 %1, %2, 63"
        : "=s"(lo), "=s"(hi) : "v"(x));
    return __int_as_float(hiHalf ? hi : lo);
}

// Shift whole wave down one lane (lane i <- lane i-1); wave lane 0 gets 0.
__device__ __forceinline__ float wave_shr1(float x) {
    return __int_as_float(
        __builtin_amdgcn_update_dpp(0, __float_as_int(x), 0x138, 0xf, 0xf, false));
}

// Native HW sincos (revolutions + fract reduction).
__device__ __forceinline__ void fast_sincos(float x, float& s, float& c) {
    float r = __builtin_amdgcn_fractf(x * 0.15915494309189535f);
    s = __builtin_amdgcn_sinf(r);
    c = __builtin_amdgcn_cosf(r);
}

__global__ __launch_bounds__(BLK) void rnea_kernel(
    const float* __restrict__ q,
    const float* __restrict__ qd,
    const float* __restrict__ qdd,
    const float* __restrict__ trans,
    const float* __restrict__ mass,
    const float* __restrict__ com,
    const float* __restrict__ inertia,
    const float* __restrict__ damping,
    float* __restrict__ out,
    int Bn)
{
    const int t    = blockIdx.x * BLK + threadIdx.x;
    const int lane = threadIdx.x & 31;          // joint index
    const int hiH  = (threadIdx.x >> 5) & 1;    // which 32-lane segment
    const int half = Bn >> 1;
    const int r0   = t >> 5;
    if (r0 >= half) return;
    const size_t i0 = (size_t)r0 * NJ + lane;   // coalesced
    const size_t i1 = i0 + (size_t)half * NJ;   // coalesced

    // Row pair packed as f2 = (row0, row1); all pointwise math is identical
    // per row -> clean v_pk_* SIMD2, no component mixing ever.
    f2 qv   = mk2(q  [i0], q  [i1]);
    f2 qdv  = mk2(qd [i0], qd [i1]);
    f2 qddv = mk2(qdd[i0], qdd[i1]);

    // Per-joint constants (L1-hot broadcast lines), shared by both rows.
    float m    = mass[lane];
    float cx   = com[3*lane+0], cy = com[3*lane+1];
    float mcx  = m*cx, mcy = m*cy;
    float i2zz = fmaf(m, cx*cx + cy*cy, inertia[9*lane+8]);   // Ibar_zz
    float px   = trans[3*lane+0], py = trans[3*lane+1];
    float damp = damping[lane];
    const bool seg0 = (lane == 0);

    // ---- Stage A: 6 independent prefix scans (phi, w, alpha x 2 rows).
    float phi0 = qv.x,  phi1 = qv.y;
    float wI0  = qdv.x, wI1  = qdv.y;
    float aI0  = qddv.x, aI1 = qddv.y;
    scan6(phi0, phi1, wI0, wI1, aI0, aI1);
    f2 wI = mk2(wI0, wI1), aI = mk2(aI0, aI1);
    f2 wP = wI - qdv;                           // w_{j-1}   (pk)
    f2 aP = aI - qddv;                          // alpha_{j-1}

    float c0, s0, c1, s1;
    fast_sincos(phi0, s0, c0);
    fast_sincos(phi1, s1, c1);
    f2 c  = mk2(c0, c1), s = mk2(s0, s1);
    f2 cp = mk2(wave_shr1(c0), wave_shr1(c1));
    f2 sp = mk2(wave_shr1(s0), wave_shr1(s1));
    if (seg0) { cp = 1.f; sp = 0.f; }

    // d_j = Rz(phi_{j-1}) * p_j    (pk: 2 ops each)
    f2 dx = cp*px - sp*py;
    f2 dy = sp*px + cp*py;

    // ---- Stage B: VL scans (4 chains); integrands pk.
    f2 ux = -wP*dy, uy = wP*dx;
    float VLx0 = ux.x, VLy0 = uy.x, VLx1 = ux.y, VLy1 = uy.y;
    scan4(VLx0, VLy0, VLx1, VLy1);
    f2 VLx = mk2(VLx0, VLx1), VLy = mk2(VLy0, VLy1);

    // ---- Stage C: AL scans (4 chains); integrands pk.
    f2 gx = qdv*VLy - aP*dy;
    f2 gy = -qdv*VLx + aP*dx;
    float ALx0 = gx.x, ALy0 = gy.x, ALx1 = gx.y, ALy1 = gy.y;
    scan4(ALx0, ALy0, ALx1, ALy1);
    f2 ALx = mk2(ALx0, ALx1), ALy = mk2(ALy0, ALy1);

    // ---- Backward (world frame, z-chain only); all pk.
    f2 mcwx = c*mcx - s*mcy;                    // Rz(phi_j) * mc
    f2 mcwy = s*mcx + c*mcy;

    f2 fv_lx = m*VLx + wI*mcwy;
    f2 fv_ly = m*VLy - wI*mcwx;

    f2 llx = m*ALx + aI*mcwy - wI*fv_ly;
    f2 lly = m*ALy - aI*mcwx + wI*fv_lx;

    // ---- Stage D: force prefix scans (4 chains); suffix via totals.
    float Px0 = llx.x, Py0 = lly.x, Px1 = llx.y, Py1 = lly.y;
    scan4(Px0, Py0, Px1, Py1);
    f2 Px = mk2(Px0, Px1), Py = mk2(Py0, Py1);
    f2 Tx = mk2(seg_total(Px0, hiH), seg_total(Px1, hiH));
    f2 Ty = mk2(seg_total(Py0, hiH), seg_total(Py1, hiH));
    f2 Fx = Tx - Px + llx;
    f2 Fy = Ty - Py + lly;

    // ---- Stage E: z-moment chains (2 chains); integrands pk.
    f2 a = aI*i2zz + mcwx*ALy - mcwy*ALx + VLx*fv_ly - VLy*fv_lx;
    f2 b = dx*Fy - dy*Fx;
    f2 ab = a + b;
    float Pr0 = ab.x, Pr1 = ab.y;
    scan2(Pr0, Pr1);
    f2 Pr = mk2(Pr0, Pr1);
    f2 Tr = mk2(seg_total(Pr0, hiH), seg_total(Pr1, hiH));
    // Nz = suffix(a+b) - b = T - Pr + a
    f2 Nz = Tr - Pr + a;

    f2 tau = damp*qdv + Nz;
    out[i0] = tau.x;
    out[i1] = tau.y;
}

extern "C" void kernel_launch(void* const* d_in, const int* in_sizes, int n_in,
                              void* d_out, int out_size, void* d_ws, size_t ws_size,
                              hipStream_t stream) {
    const float* q       = (const float*)d_in[0];
    const float* qd      = (const float*)d_in[1];
    const float* qdd     = (const float*)d_in[2];
    const float* trans   = (const float*)d_in[3];
    const float* mass    = (const float*)d_in[4];
    const float* com     = (const float*)d_in[5];
    const float* inertia = (const float*)d_in[6];
    const float* damping = (const float*)d_in[7];
    float* out = (float*)d_out;

    int Bn = in_sizes[0] / NJ;
    long long threads = (long long)(Bn/2) * 32;
    int grid = (int)((threads + BLK - 1) / BLK);
    hipLaunchKernelGGL(rnea_kernel, dim3(grid), dim3(BLK), 0, stream,
                       q, qd, qdd, trans, mass, com, inertia, damping, out, Bn);
}